// Round 1
// baseline (1357.396 us; speedup 1.0000x reference)
//
#include <hip/hip_runtime.h>
#include <hip/hip_bf16.h>

#define BB 32
#define LL 12
#define NN 1024
#define FF 2
#define HH 128
#define HORN 12
#define G3 384
#define CAP 128

typedef unsigned short u16;
typedef unsigned int u32;
typedef __attribute__((ext_vector_type(8))) short short8;
typedef __attribute__((ext_vector_type(4))) float f32x4;

// ---- build ELL (per-row compacted sparse A) ----
__global__ void build_ell(const float* __restrict__ A, int* __restrict__ cnt,
                          int* __restrict__ idx, float* __restrict__ val) {
    int i = blockIdx.x;
    __shared__ int c;
    if (threadIdx.x == 0) c = 0;
    __syncthreads();
    for (int j = threadIdx.x; j < NN; j += blockDim.x) {
        float a = A[i * NN + j];
        if (a != 0.0f) {
            int s = atomicAdd(&c, 1);
            if (s < CAP) { idx[i * CAP + s] = j; val[i * CAP + s] = a; }
        }
    }
    __syncthreads();
    if (threadIdx.x == 0) cnt[i] = (c < CAP) ? c : CAP;
}

// ---- W_h [128][384] fp32 -> W_hT [384][128] bf16 ----
__global__ void prep_whT(const float* __restrict__ W_h, u16* __restrict__ whT) {
    int t = blockIdx.x * blockDim.x + threadIdx.x;
    if (t >= HH * G3) return;
    int c = t / HH, k = t % HH;
    __hip_bfloat16 hb = __float2bfloat16(W_h[k * G3 + c]);
    whT[c * HH + k] = __builtin_bit_cast(u16, hb);
}

// ---- one GRU step: SpMM gather -> LDS bf16 tile -> MFMA gates -> h_new ----
__global__ __launch_bounds__(512) void gru_step(
    const float* __restrict__ h_old, float* __restrict__ h_new,
    const int* __restrict__ ecnt, const int* __restrict__ eidx,
    const float* __restrict__ eval, const u16* __restrict__ whT,
    const float* __restrict__ x, const float* __restrict__ W_x,
    const float* __restrict__ b_x, const float* __restrict__ b_h, int t) {
    __shared__ __align__(16) u16 ah_lds[64 * 128];

    int bid = blockIdx.x;
    int swz = (bid & 7) * 64 + (bid >> 3);  // XCD-chunked: 64 contiguous blocks/XCD
    int b = swz >> 4;
    int itile = swz & 15;
    int i0 = itile * 64;
    int tid = threadIdx.x;
    int w = tid >> 6, lane = tid & 63;

    // ---------- phase 1: Ah rows (fp32 gather, bf16 into swizzled LDS) ----------
    const float* hb = h_old + (size_t)b * NN * HH;
    for (int rr = 0; rr < 8; ++rr) {
        int r = w * 8 + rr;
        int i = i0 + r;
        int cnt = ecnt[i];
        const int* jrow = eidx + i * CAP;
        const float* arow = eval + i * CAP;
        float ah0 = 0.f, ah1 = 0.f;
        int s = 0;
        for (; s + 4 <= cnt; s += 4) {
            int j0 = jrow[s], j1 = jrow[s + 1], j2 = jrow[s + 2], j3 = jrow[s + 3];
            float a0 = arow[s], a1 = arow[s + 1], a2 = arow[s + 2], a3 = arow[s + 3];
            float2 v0 = *(const float2*)(hb + j0 * HH + 2 * lane);
            float2 v1 = *(const float2*)(hb + j1 * HH + 2 * lane);
            float2 v2 = *(const float2*)(hb + j2 * HH + 2 * lane);
            float2 v3 = *(const float2*)(hb + j3 * HH + 2 * lane);
            ah0 = fmaf(a0, v0.x, ah0); ah1 = fmaf(a0, v0.y, ah1);
            ah0 = fmaf(a1, v1.x, ah0); ah1 = fmaf(a1, v1.y, ah1);
            ah0 = fmaf(a2, v2.x, ah0); ah1 = fmaf(a2, v2.y, ah1);
            ah0 = fmaf(a3, v3.x, ah0); ah1 = fmaf(a3, v3.y, ah1);
        }
        for (; s < cnt; ++s) {
            int j = jrow[s]; float a = arow[s];
            float2 v = *(const float2*)(hb + j * HH + 2 * lane);
            ah0 = fmaf(a, v.x, ah0); ah1 = fmaf(a, v.y, ah1);
        }
        u32 p = (u32)__builtin_bit_cast(u16, __float2bfloat16(ah0)) |
                ((u32)__builtin_bit_cast(u16, __float2bfloat16(ah1)) << 16);
        int off = r * 256 + ((4 * lane) ^ ((r & 7) << 4));
        *(u32*)((char*)ah_lds + off) = p;
    }
    __syncthreads();

    // ---------- phase 2: gates = Ah @ W_h (bf16 MFMA) + epilogue ----------
    int rt = w >> 1;            // 4 row-tiles of 16
    int ctz0 = (w & 1) * 4;     // split 8 z-coltiles across wave pairs
    int lrow = lane >> 4;       // k-group / D-row-group
    int lcol = lane & 15;

    short8 af[4];
    int arl = rt * 16 + lcol;   // A-frag row = lane&15
#pragma unroll
    for (int ks = 0; ks < 4; ++ks) {
        int kb = ks * 64 + lrow * 16;  // byte offset of k within row
        int off = arl * 256 + (kb ^ ((arl & 7) << 4));
        af[ks] = __builtin_bit_cast(short8, *(const uint4*)((const char*)ah_lds + off));
    }

#pragma unroll
    for (int cz = 0; cz < 4; ++cz) {
        int ctz = ctz0 + cz;
        int hh = ctz * 16 + lcol;  // 0..127
        f32x4 az = {0.f, 0.f, 0.f, 0.f}, ar = {0.f, 0.f, 0.f, 0.f}, an = {0.f, 0.f, 0.f, 0.f};
#pragma unroll
        for (int ks = 0; ks < 4; ++ks) {
            int ko = ks * 32 + lrow * 8;  // u16 index within W_hT row
            short8 fz = __builtin_bit_cast(short8, *(const uint4*)(whT + (size_t)hh * HH + ko));
            short8 fr = __builtin_bit_cast(short8, *(const uint4*)(whT + (size_t)(128 + hh) * HH + ko));
            short8 fn = __builtin_bit_cast(short8, *(const uint4*)(whT + (size_t)(256 + hh) * HH + ko));
            az = __builtin_amdgcn_mfma_f32_16x16x32_bf16(af[ks], fz, az, 0, 0, 0);
            ar = __builtin_amdgcn_mfma_f32_16x16x32_bf16(af[ks], fr, ar, 0, 0, 0);
            an = __builtin_amdgcn_mfma_f32_16x16x32_bf16(af[ks], fn, an, 0, 0, 0);
        }
        float bxz = b_x[hh], bxr = b_x[128 + hh], bxn = b_x[256 + hh];
        float bhz = b_h[hh], bhr = b_h[128 + hh], bhn = b_h[256 + hh];
        float wx0z = W_x[hh], wx0r = W_x[128 + hh], wx0n = W_x[256 + hh];
        float wx1z = W_x[G3 + hh], wx1r = W_x[G3 + 128 + hh], wx1n = W_x[G3 + 256 + hh];
#pragma unroll
        for (int ri = 0; ri < 4; ++ri) {
            int rl = rt * 16 + lrow * 4 + ri;  // D row = (lane>>4)*4 + reg
            int i = i0 + rl;
            const float* xp = x + ((size_t)(b * LL + t) * NN + i) * FF;
            float x0 = xp[0], x1 = xp[1];
            float zin = az[ri] + bhz + fmaf(x0, wx0z, fmaf(x1, wx1z, bxz));
            float rin = ar[ri] + bhr + fmaf(x0, wx0r, fmaf(x1, wx1r, bxr));
            float z = 1.f / (1.f + __expf(-zin));
            float rg = 1.f / (1.f + __expf(-rin));
            float nin = fmaf(rg, an[ri] + bhn, fmaf(x0, wx0n, fmaf(x1, wx1n, bxn)));
            nin = fmaxf(nin, -40.f);
            float e = __expf(-2.f * nin);
            float n = (1.f - e) / (1.f + e);
            size_t hidx = ((size_t)b * NN + i) * HH + hh;
            float hold = h_old[hidx];
            h_new[hidx] = fmaf(z, hold - n, n);
        }
    }
}

// ---- head: y[b,hor,i] = h[b,i,:] @ W_head[:,hor] + b_head ----
__global__ void head_kernel(const float* __restrict__ hfin, const float* __restrict__ W_head,
                            const float* __restrict__ b_head, float* __restrict__ out) {
    int gw = blockIdx.x * (blockDim.x >> 6) + (threadIdx.x >> 6);
    int lane = threadIdx.x & 63;
    int b = gw >> 10;
    int i = gw & 1023;
    size_t hbase = ((size_t)b * NN + i) * HH;
    float h0v = hfin[hbase + lane];
    float h1v = hfin[hbase + 64 + lane];
#pragma unroll
    for (int hor = 0; hor < HORN; ++hor) {
        float p = fmaf(h0v, W_head[lane * HORN + hor], h1v * W_head[(64 + lane) * HORN + hor]);
#pragma unroll
        for (int o = 32; o > 0; o >>= 1) p += __shfl_down(p, o);
        if (lane == 0) out[((size_t)b * HORN + hor) * NN + i] = p + b_head[hor];
    }
}

extern "C" void kernel_launch(void* const* d_in, const int* in_sizes, int n_in,
                              void* d_out, int out_size, void* d_ws, size_t ws_size,
                              hipStream_t stream) {
    const float* x = (const float*)d_in[0];
    const float* A = (const float*)d_in[1];
    const float* W_x = (const float*)d_in[2];
    const float* b_x = (const float*)d_in[3];
    const float* W_h = (const float*)d_in[4];
    const float* b_h = (const float*)d_in[5];
    const float* W_head = (const float*)d_in[6];
    const float* b_head = (const float*)d_in[7];
    float* out = (float*)d_out;
    char* ws = (char*)d_ws;

    // workspace layout (bytes)
    float* hb0 = (float*)(ws + 0);              // 16 MB
    float* hb1 = (float*)(ws + 16777216);       // 16 MB
    int*   eidx = (int*)(ws + 33554432);        // 1024*128*4 = 512 KB
    float* eval = (float*)(ws + 34078720);      // 512 KB
    int*   ecnt = (int*)(ws + 34603008);        // 4 KB
    u16*   whT  = (u16*)(ws + 34607104);        // 96 KB

    hipMemsetAsync(hb0, 0, 16777216, stream);
    build_ell<<<NN, 256, 0, stream>>>(A, ecnt, eidx, eval);
    prep_whT<<<(HH * G3 + 255) / 256, 256, 0, stream>>>(W_h, whT);

    float* ho = hb0;
    float* hn = hb1;
    for (int t = 0; t < LL; ++t) {
        gru_step<<<512, 512, 0, stream>>>(ho, hn, ecnt, eidx, eval, whT, x, W_x, b_x, b_h, t);
        float* tmp = ho; ho = hn; hn = tmp;
    }
    head_kernel<<<BB * NN / 4, 256, 0, stream>>>(ho, W_head, b_head, out);
}

// Round 2
// 432.416 us; speedup vs baseline: 3.1391x; 3.1391x over previous
//
#include <hip/hip_runtime.h>
#include <hip/hip_bf16.h>

#define BB 32
#define LL 12
#define NN 1024
#define FF 2
#define HH 128
#define HORN 12
#define G3 384

typedef unsigned short u16;
typedef unsigned int u32;
typedef __attribute__((ext_vector_type(8))) short short8;
typedef __attribute__((ext_vector_type(4))) float f32x4;

__device__ __forceinline__ u16 to_bf16(float f) {
    return __builtin_bit_cast(u16, __float2bfloat16(f));
}

// ---- A fp32 [1024][1024] -> bf16 ----
__global__ void prep_abf(const float* __restrict__ A, u16* __restrict__ Abf) {
    int t = blockIdx.x * blockDim.x + threadIdx.x;  // 262144 threads, 4 elems each
    float4 v = ((const float4*)A)[t];
    ushort4 o;
    o.x = to_bf16(v.x); o.y = to_bf16(v.y); o.z = to_bf16(v.z); o.w = to_bf16(v.w);
    ((ushort4*)Abf)[t] = o;
}

// ---- W_h [128][384] fp32 -> W_hT [384][128] bf16 ----
__global__ void prep_whT(const float* __restrict__ W_h, u16* __restrict__ whT) {
    int t = blockIdx.x * blockDim.x + threadIdx.x;
    if (t >= HH * G3) return;
    int c = t / HH, k = t % HH;
    whT[c * HH + k] = to_bf16(W_h[k * G3 + c]);
}

// ---- one GRU step: dense Ah = A@h (MFMA, K=1024) -> gate GEMM -> epilogue ----
// block: batch b, rows [i0, i0+64); 512 threads = 8 waves.
__global__ __launch_bounds__(512) void gru_step(
    const u16* __restrict__ Abf, const u16* __restrict__ hT_old,
    const float* __restrict__ h_old, float* __restrict__ h_new,
    u16* __restrict__ hT_new, const u16* __restrict__ whT,
    const float* __restrict__ x, const float* __restrict__ W_x,
    const float* __restrict__ b_x, const float* __restrict__ b_h, int t) {
    // LDS: A-stage [64][64] 8K | hT-stage [128][64] 16K | Ah [64][128] 16K | T [128][64] 16K
    __shared__ __align__(16) char smem[57344];

    int bid = blockIdx.x;
    int swz = (bid & 7) * 64 + (bid >> 3);  // 64 consecutive per XCD -> 4 batches/XCD in L2
    int b = swz >> 4;
    int i0 = (swz & 15) * 64;
    int tid = threadIdx.x;
    int w = tid >> 6, lane = tid & 63;
    int lcol = lane & 15, kgrp = lane >> 4;

    // ---- staging lane mapping (reg-staged, swizzled ds_write, swizzled ds_read) ----
    int a_lr = w * 8 + (lane >> 3);        // A-tile row 0..63
    int a_cb = (lane & 7) * 16;            // byte col within 128B row
    const u16* a_src = Abf + (size_t)(i0 + a_lr) * 1024 + (lane & 7) * 8;
    u32 a_wo = (u32)(a_lr * 128 + (a_cb ^ ((a_lr & 7) << 4)));

    int h_n0 = w * 16 + (lane >> 3);       // hT-tile rows n0, n0+8
    const u16* h_src0 = hT_old + ((size_t)b * 128 + h_n0) * 1024 + (lane & 7) * 8;
    const u16* h_src1 = h_src0 + 8 * 1024;
    u32 h_wo0 = (u32)(8192 + h_n0 * 128 + (a_cb ^ ((h_n0 & 7) << 4)));
    u32 h_wo1 = h_wo0 + 1024;              // n0+8: same swizzle bits (n&7 unchanged)

    // ---- GEMM1: Ah[64][128] = A[i0:,:] @ h_b ----
    int mt = w >> 1, nh = w & 1;           // wave: 16 rows x 64 cols
    int ar = mt * 16 + lcol;
    u32 af_base = (u32)(ar * 128);
    u32 af_swz = (u32)((ar & 7) << 4);

    f32x4 acc[4] = {{0.f,0.f,0.f,0.f},{0.f,0.f,0.f,0.f},{0.f,0.f,0.f,0.f},{0.f,0.f,0.f,0.f}};

    uint4 ra = *(const uint4*)a_src;
    uint4 rh0 = *(const uint4*)h_src0;
    uint4 rh1 = *(const uint4*)h_src1;

    for (int ks16 = 0; ks16 < 16; ++ks16) {
        *(uint4*)(smem + a_wo) = ra;
        *(uint4*)(smem + h_wo0) = rh0;
        *(uint4*)(smem + h_wo1) = rh1;
        __syncthreads();
        if (ks16 < 15) {  // issue next-tile loads early; latency hides under MFMA
            int j1 = (ks16 + 1) * 64;
            ra = *(const uint4*)(a_src + j1);
            rh0 = *(const uint4*)(h_src0 + j1);
            rh1 = *(const uint4*)(h_src1 + j1);
        }
        short8 af0 = *(const short8*)(smem + af_base + ((kgrp * 16) ^ af_swz));
        short8 af1 = *(const short8*)(smem + af_base + ((64 + kgrp * 16) ^ af_swz));
#pragma unroll
        for (int nt = 0; nt < 4; ++nt) {
            int n = nh * 64 + nt * 16 + lcol;
            u32 bb = (u32)(8192 + n * 128);
            u32 bswz = (u32)((n & 7) << 4);
            short8 b0 = *(const short8*)(smem + bb + ((kgrp * 16) ^ bswz));
            short8 b1 = *(const short8*)(smem + bb + ((64 + kgrp * 16) ^ bswz));
            acc[nt] = __builtin_amdgcn_mfma_f32_16x16x32_bf16(af0, b0, acc[nt], 0, 0, 0);
            acc[nt] = __builtin_amdgcn_mfma_f32_16x16x32_bf16(af1, b1, acc[nt], 0, 0, 0);
        }
        __syncthreads();
    }

    // ---- Ah -> LDS (bf16, swizzled [64][128]) ----
#pragma unroll
    for (int nt = 0; nt < 4; ++nt) {
#pragma unroll
        for (int ri = 0; ri < 4; ++ri) {
            int row = mt * 16 + kgrp * 4 + ri;
            int col = nh * 64 + nt * 16 + lcol;
            *(u16*)(smem + 24576 + row * 256 + ((2 * col) ^ ((row & 7) << 4))) = to_bf16(acc[nt][ri]);
        }
    }
    __syncthreads();

    // ---- GEMM2: gates = Ah @ W_h; wave owns hh-tile [w*16, w*16+16) x 3 gates x 64 rows ----
    int hh = w * 16 + lcol;
    f32x4 acc2[4][3];
#pragma unroll
    for (int rt = 0; rt < 4; ++rt)
#pragma unroll
        for (int g = 0; g < 3; ++g) acc2[rt][g] = (f32x4){0.f, 0.f, 0.f, 0.f};

#pragma unroll
    for (int g = 0; g < 3; ++g) {
        short8 bw[4];
#pragma unroll
        for (int ks = 0; ks < 4; ++ks)
            bw[ks] = *(const short8*)(whT + (size_t)(g * 128 + hh) * 128 + ks * 32 + kgrp * 8);
#pragma unroll
        for (int rt = 0; rt < 4; ++rt) {
            int r2 = rt * 16 + lcol;
            u32 abase = (u32)(24576 + r2 * 256);
            u32 aswz = (u32)((r2 & 7) << 4);
#pragma unroll
            for (int ks = 0; ks < 4; ++ks) {
                short8 a2 = *(const short8*)(smem + abase + ((ks * 64 + kgrp * 16) ^ aswz));
                acc2[rt][g] = __builtin_amdgcn_mfma_f32_16x16x32_bf16(a2, bw[ks], acc2[rt][g], 0, 0, 0);
            }
        }
    }

    // ---- epilogue: gates + blend; write h_new fp32 + transposed bf16 via LDS ----
    float bxz = b_x[hh], bxr = b_x[128 + hh], bxn = b_x[256 + hh];
    float bhz = b_h[hh], bhr = b_h[128 + hh], bhn = b_h[256 + hh];
    float wx0z = W_x[hh], wx0r = W_x[128 + hh], wx0n = W_x[256 + hh];
    float wx1z = W_x[G3 + hh], wx1r = W_x[G3 + 128 + hh], wx1n = W_x[G3 + 256 + hh];
#pragma unroll
    for (int rt = 0; rt < 4; ++rt) {
#pragma unroll
        for (int ri = 0; ri < 4; ++ri) {
            int rl = rt * 16 + kgrp * 4 + ri;
            int i = i0 + rl;
            const float* xp = x + ((size_t)(b * LL + t) * NN + i) * FF;
            float x0 = xp[0], x1 = xp[1];
            float zin = acc2[rt][0][ri] + bhz + fmaf(x0, wx0z, fmaf(x1, wx1z, bxz));
            float rin = acc2[rt][1][ri] + bhr + fmaf(x0, wx0r, fmaf(x1, wx1r, bxr));
            float z = 1.f / (1.f + __expf(-zin));
            float rg = 1.f / (1.f + __expf(-rin));
            float nin = fmaf(rg, acc2[rt][2][ri] + bhn, fmaf(x0, wx0n, fmaf(x1, wx1n, bxn)));
            nin = fmaxf(nin, -40.f);
            float e = __expf(-2.f * nin);
            float n = (1.f - e) / (1.f + e);
            size_t hidx = ((size_t)b * NN + i) * HH + hh;
            float hold = h_old[hidx];
            float hv = fmaf(z, hold - n, n);
            h_new[hidx] = hv;
            *(u16*)(smem + 40960 + hh * 128 + ((2 * rl) ^ ((hh & 7) << 4))) = to_bf16(hv);
        }
    }
    __syncthreads();
    // coalesced copy-out: hT_new[b][n][i0:i0+64]
#pragma unroll
    for (int c = 0; c < 2; ++c) {
        int o = tid * 32 + c * 16;
        int nrow = o >> 7, cbb = o & 127;
        uint4 v = *(const uint4*)(smem + 40960 + nrow * 128 + (cbb ^ ((nrow & 7) << 4)));
        *(uint4*)((char*)(hT_new + ((size_t)b * 128 + nrow) * 1024 + i0) + cbb) = v;
    }
}

// ---- head: y[b,hor,i] = h[b,i,:] @ W_head[:,hor] + b_head ----
__global__ void head_kernel(const float* __restrict__ hfin, const float* __restrict__ W_head,
                            const float* __restrict__ b_head, float* __restrict__ out) {
    int gw = blockIdx.x * (blockDim.x >> 6) + (threadIdx.x >> 6);
    int lane = threadIdx.x & 63;
    int b = gw >> 10;
    int i = gw & 1023;
    size_t hbase = ((size_t)b * NN + i) * HH;
    float h0v = hfin[hbase + lane];
    float h1v = hfin[hbase + 64 + lane];
#pragma unroll
    for (int hor = 0; hor < HORN; ++hor) {
        float p = fmaf(h0v, W_head[lane * HORN + hor], h1v * W_head[(64 + lane) * HORN + hor]);
#pragma unroll
        for (int o = 32; o > 0; o >>= 1) p += __shfl_down(p, o);
        if (lane == 0) out[((size_t)b * HORN + hor) * NN + i] = p + b_head[hor];
    }
}

extern "C" void kernel_launch(void* const* d_in, const int* in_sizes, int n_in,
                              void* d_out, int out_size, void* d_ws, size_t ws_size,
                              hipStream_t stream) {
    const float* x = (const float*)d_in[0];
    const float* A = (const float*)d_in[1];
    const float* W_x = (const float*)d_in[2];
    const float* b_x = (const float*)d_in[3];
    const float* W_h = (const float*)d_in[4];
    const float* b_h = (const float*)d_in[5];
    const float* W_head = (const float*)d_in[6];
    const float* b_head = (const float*)d_in[7];
    float* out = (float*)d_out;
    char* ws = (char*)d_ws;

    // workspace layout
    float* hb0 = (float*)(ws + 0);               // 16 MB fp32 h
    float* hb1 = (float*)(ws + 16777216);        // 16 MB
    u16*   hT0 = (u16*)(ws + 33554432);          // 8 MB bf16 h^T
    u16*   hT1 = (u16*)(ws + 41943040);          // 8 MB
    u16*   Abf = (u16*)(ws + 50331648);          // 2 MB bf16 A
    u16*   whT = (u16*)(ws + 52428800);          // 96 KB

    hipMemsetAsync(hb0, 0, 16777216, stream);
    hipMemsetAsync(hT0, 0, 8388608, stream);
    prep_abf<<<1024, 256, 0, stream>>>(A, Abf);
    prep_whT<<<(HH * G3 + 255) / 256, 256, 0, stream>>>(W_h, whT);

    float* ho = hb0; float* hn = hb1;
    u16* hTo = hT0; u16* hTn = hT1;
    for (int t = 0; t < LL; ++t) {
        gru_step<<<512, 512, 0, stream>>>(Abf, hTo, ho, hn, hTn, whT, x, W_x, b_x, b_h, t);
        float* tmp = ho; ho = hn; hn = tmp;
        u16* tmpT = hTo; hTo = hTn; hTn = tmpT;
    }
    head_kernel<<<BB * NN / 4, 256, 0, stream>>>(ho, W_head, b_head, out);
}